// Round 4
// baseline (389.364 us; speedup 1.0000x reference)
//
#include <hip/hip_runtime.h>
#include <hip/hip_bf16.h>

using bf16x8 = __attribute__((ext_vector_type(8))) short;
using f32x4  = __attribute__((ext_vector_type(4))) float;
using f32x16 = __attribute__((ext_vector_type(16))) float;
using u32x4  = __attribute__((ext_vector_type(4))) unsigned;
using i32x4  = __attribute__((ext_vector_type(4))) int;

static constexpr int B_ = 2, S_ = 2048, D_ = 1024, H_ = 16, HD_ = 64;
static constexpr int BS_ = B_ * S_;                  // 4096 rows
static constexpr float CP_ = 0.18033688011112042f;   // log2(e)/sqrt(64)

// ---------- helpers ----------
__device__ __forceinline__ unsigned short bfbits(float x) {
    unsigned u = __builtin_bit_cast(unsigned, x);
    unsigned r = (u + 0x7fffu + ((u >> 16) & 1u)) >> 16;   // RNE
    return (unsigned short)r;
}
__device__ __forceinline__ short bfs(float x) { return (short)bfbits(x); }

__device__ __forceinline__ unsigned cvt_pk_bf16(float lo, float hi) {
    unsigned r;
    asm("v_cvt_pk_bf16_f32 %0, %1, %2" : "=v"(r) : "v"(lo), "v"(hi));
    return r;
}
__device__ __forceinline__ void gload_lds16(const short* g, short* l) {
    __builtin_amdgcn_global_load_lds(
        (const __attribute__((address_space(1))) void*)g,
        (__attribute__((address_space(3))) void*)l, 16, 0, 0);
}

// ---------- cast tokens f32 -> bf16 ----------
__global__ void cast_f32_bf16_kernel(const float* __restrict__ in,
                                     short* __restrict__ out, int n8) {
    int i = blockIdx.x * blockDim.x + threadIdx.x;
    if (i >= n8) return;
    const float4* p = (const float4*)in + (size_t)i * 2;
    float4 a = p[0], b = p[1];
    short tmp[8] = { bfs(a.x), bfs(a.y), bfs(a.z), bfs(a.w),
                     bfs(b.x), bfs(b.y), bfs(b.z), bfs(b.w) };
    *(int4*)(out + (size_t)i * 8) = *(int4*)tmp;
}

// ---------- transpose+cast weight: in [R][C] f32 -> out [C][R] bf16 ----------
__global__ void transpose_cast_f32_kernel(const float* __restrict__ in,
                                          short* __restrict__ out, int R, int C) {
    __shared__ short tile[64][65];
    int t = threadIdx.x;
    int r0 = blockIdx.y * 64, c0 = blockIdx.x * 64;
    int lr = t >> 2, lc0 = (t & 3) * 16;
    const float4* src = (const float4*)(in + (size_t)(r0 + lr) * C + c0 + lc0);
#pragma unroll
    for (int v = 0; v < 4; v++) {
        float4 f = src[v];
        tile[lr][lc0 + v * 4 + 0] = bfs(f.x);
        tile[lr][lc0 + v * 4 + 1] = bfs(f.y);
        tile[lr][lc0 + v * 4 + 2] = bfs(f.z);
        tile[lr][lc0 + v * 4 + 3] = bfs(f.w);
    }
    __syncthreads();
    int oc = t >> 2, os0 = (t & 3) * 16;
    short tmp[16];
#pragma unroll
    for (int j = 0; j < 16; j++) tmp[j] = tile[os0 + j][oc];
    short* dst = out + (size_t)(c0 + oc) * R + r0 + os0;
    *(int4*)(dst) = *(int4*)(tmp);
    *(int4*)(dst + 8) = *(int4*)(tmp + 8);
}

// ---------- transpose V (bf16): [B*S][D] head-cols -> Vt[b][h][64][S] ----------
__global__ void transpose_v_kernel(const short* __restrict__ V,
                                   short* __restrict__ Vt) {
    __shared__ short tile[64][65];
    int t = threadIdx.x;
    int sblk = blockIdx.x * 64;
    int h = blockIdx.y, b = blockIdx.z;
    int lr = t >> 2, lc0 = (t & 3) * 16;
    const short* src = V + (size_t)(b * S_ + sblk + lr) * D_ + h * HD_ + lc0;
    short tin[16];
    *(int4*)(tin) = *(const int4*)(src);
    *(int4*)(tin + 8) = *(const int4*)(src + 8);
#pragma unroll
    for (int j = 0; j < 16; j++) tile[lr][lc0 + j] = tin[j];
    __syncthreads();
    int od = t >> 2, os0 = (t & 3) * 16;
    short tmp[16];
#pragma unroll
    for (int j = 0; j < 16; j++) tmp[j] = tile[os0 + j][od];
    short* dst = Vt + ((size_t)(b * H_ + h) * HD_ + od) * S_ + sblk + os0;
    *(int4*)(dst) = *(int4*)(tmp);
    *(int4*)(dst + 8) = *(int4*)(tmp + 8);
}

// ---------- bf16 GEMM: C[M][N] = (A[M][K] * BT[N][K]^T + bias) * scale ----------
template <int OUT_F32>
__global__ __launch_bounds__(256, 2)
void gemm_bt_kernel(const short* __restrict__ A, const short* __restrict__ BT,
                    const float* __restrict__ bias, void* __restrict__ Cout,
                    int M, int N, int K, float scale) {
    __shared__ __align__(16) short As[128 * 32];
    __shared__ __align__(16) short Bs[128 * 32];
    int t = threadIdx.x;
    int w = t >> 6, l = t & 63;
    int lq = l & 15, g = l >> 4;
    int rowBase = blockIdx.y * 128, colBase = blockIdx.x * 128;
    int wrow = (w >> 1) * 64, wcol = (w & 1) * 64;
    f32x4 acc[4][4] = {};
    const short* a0 = A + (size_t)(rowBase + (t >> 2)) * K + (t & 3) * 8;
    const short* a1 = a0 + (size_t)64 * K;
    const short* b0 = BT + (size_t)(colBase + (t >> 2)) * K + (t & 3) * 8;
    const short* b1 = b0 + (size_t)64 * K;
    for (int kt = 0; kt < K; kt += 32) {
        __syncthreads();
        gload_lds16(a0 + kt, &As[t * 8]);
        gload_lds16(a1 + kt, &As[t * 8 + 2048]);
        gload_lds16(b0 + kt, &Bs[t * 8]);
        gload_lds16(b1 + kt, &Bs[t * 8 + 2048]);
        __syncthreads();
        bf16x8 af[4], bfr[4];
#pragma unroll
        for (int mi = 0; mi < 4; mi++)
            af[mi] = *(const bf16x8*)(&As[(wrow + mi * 16 + lq) * 32 + 8 * g]);
#pragma unroll
        for (int ni = 0; ni < 4; ni++)
            bfr[ni] = *(const bf16x8*)(&Bs[(wcol + ni * 16 + lq) * 32 + 8 * g]);
#pragma unroll
        for (int mi = 0; mi < 4; mi++)
#pragma unroll
            for (int ni = 0; ni < 4; ni++)
                acc[mi][ni] = __builtin_amdgcn_mfma_f32_16x16x32_bf16(
                    af[mi], bfr[ni], acc[mi][ni], 0, 0, 0);
    }
#pragma unroll
    for (int mi = 0; mi < 4; mi++)
#pragma unroll
        for (int ni = 0; ni < 4; ni++) {
            int col = colBase + wcol + ni * 16 + lq;
            float bcol = bias[col];
#pragma unroll
            for (int r = 0; r < 4; r++) {
                int row = rowBase + wrow + mi * 16 + 4 * g + r;
                float v = (acc[mi][ni][r] + bcol) * scale;
                if (OUT_F32)
                    ((float*)Cout)[(size_t)row * N + col] = v;
                else
                    ((short*)Cout)[(size_t)row * N + col] = bfs(v);
            }
        }
}

// ---------- fused two-branch attention, 32x32 MFMA, in-register softmax ----------
// Wave = 32 q-rows of one head. Swapped QK^T (mfma32(K,Q)) => st[r] =
// S[key=(r&3)+8*(r>>2)+4*h2][q=l&31]. Q pre-scaled by log2(e)/sqrt(64), so
// p = exp2(+/-st) (one v_exp_f32 each).
// NO cross-lane redistribution: the pre-swap cvt_pk fragments pa are a valid
// A-operand for a key-PERMUTED contraction — lane(h2) slot j holds
// P[q][key=(j&3)+8*(j>>2)+4*h2].  We simply load V's B-fragment in the SAME
// permuted key order (two 8B loads at s-offsets +4*h2 and +8+4*h2); the MFMA
// sums over keys order-invariantly, so the result is exactly P*V.
__global__ __launch_bounds__(256, 2)
void attn_kernel(const short* __restrict__ Q, const short* __restrict__ Kb,
                 const short* __restrict__ Vt, short* __restrict__ featNeg,
                 short* __restrict__ featPos) {
    int t = threadIdx.x;
    int w = t >> 6, l = t & 63;
    int l31 = l & 31, h2 = l >> 5;
    int qtile = blockIdx.x;   // 0..15
    int hh = blockIdx.y, b = blockIdx.z;
    int qb0 = qtile * 128 + w * 32;
    const short* Qh = Q + (size_t)(b * S_) * D_ + hh * HD_;
    const short* Kh = Kb + (size_t)(b * S_) * D_ + hh * HD_;
    const short* Vh = Vt + (size_t)(b * H_ + hh) * HD_ * S_;

    // Q as B-operand frags: qa[hf] = Q[qb0+l31][16*hf + 8*h2 + j]
    bf16x8 qa[4];
    const short* qbase = Qh + (size_t)(qb0 + l31) * D_ + 8 * h2;
#pragma unroll
    for (int hf = 0; hf < 4; hf++)
        qa[hf] = *(const bf16x8*)(qbase + 16 * hf);

    f32x16 acc[2][2] = {};   // [branch][dblk]
    float lsum[2] = {0.f, 0.f};

    const short* kbase = Kh + (size_t)l31 * D_ + 8 * h2;
    // permuted V base: d-row = l31 (+32 per dblk), s-offset starts at 4*h2
    const short* vbase = Vh + (size_t)l31 * S_ + 4 * h2;

    for (int kt = 0; kt < S_; kt += 32) {
        // K as A-operand frags: ka[hf] = K[kt+l31][16*hf + 8*h2 + j]
        bf16x8 ka[4];
#pragma unroll
        for (int hf = 0; hf < 4; hf++)
            ka[hf] = *(const bf16x8*)(kbase + (size_t)kt * D_ + 16 * hf);
        // V as B-operand frags in permuted key order:
        // element j = V[kt + 16*hf + (j&3) + 8*(j>>2) + 4*h2][dblk*32 + l31]
        bf16x8 vb[2][2];
#pragma unroll
        for (int dblk = 0; dblk < 2; dblk++)
#pragma unroll
            for (int hf = 0; hf < 2; hf++) {
                const short* p = vbase + (size_t)dblk * 32 * S_ + kt + 16 * hf;
                int2 lo = *(const int2*)(p);        // keys +0..3  (+4*h2)
                int2 hi = *(const int2*)(p + 8);    // keys +8..11 (+4*h2)
                i32x4 all = {lo.x, lo.y, hi.x, hi.y};
                vb[dblk][hf] = __builtin_bit_cast(bf16x8, all);
            }

        f32x16 st = {};
#pragma unroll
        for (int hf = 0; hf < 4; hf++)
            st = __builtin_amdgcn_mfma_f32_32x32x16_bf16(ka[hf], qa[hf], st, 0, 0, 0);

#pragma unroll
        for (int br = 0; br < 2; br++) {
            unsigned c[8];
            float s0 = 0.f, s1 = 0.f;
#pragma unroll
            for (int i = 0; i < 8; i++) {
                float plo = __builtin_amdgcn_exp2f(br ? st[2 * i] : -st[2 * i]);
                float phi = __builtin_amdgcn_exp2f(br ? st[2 * i + 1] : -st[2 * i + 1]);
                if (i & 1) s1 += plo + phi; else s0 += plo + phi;
                c[i] = cvt_pk_bf16(plo, phi);
            }
            lsum[br] += s0 + s1;
            u32x4 lo4 = {c[0], c[1], c[2], c[3]};
            u32x4 hi4 = {c[4], c[5], c[6], c[7]};
            bf16x8 pa0 = __builtin_bit_cast(bf16x8, lo4);   // key-slots, tile keys 0..15
            bf16x8 pa1 = __builtin_bit_cast(bf16x8, hi4);   // key-slots, tile keys 16..31
#pragma unroll
            for (int dblk = 0; dblk < 2; dblk++) {
                acc[br][dblk] = __builtin_amdgcn_mfma_f32_32x32x16_bf16(
                    pa0, vb[dblk][0], acc[br][dblk], 0, 0, 0);
                acc[br][dblk] = __builtin_amdgcn_mfma_f32_32x32x16_bf16(
                    pa1, vb[dblk][1], acc[br][dblk], 0, 0, 0);
            }
        }
    }

#pragma unroll
    for (int br = 0; br < 2; br++) {
        float ls = lsum[br];
        ls += __shfl_xor(ls, 32);
        float inv = 1.0f / ls;
        short* dst = br ? featPos : featNeg;
#pragma unroll
        for (int r = 0; r < 16; r++) {
            int qr = (r & 3) + 8 * (r >> 2) + 4 * h2;
            float invq = __shfl(inv, qr);   // inv lives at lanes l31==q
            size_t row = (size_t)(b * S_ + qb0 + qr);
#pragma unroll
            for (int dblk = 0; dblk < 2; dblk++) {
                int col = hh * HD_ + dblk * 32 + l31;
                dst[row * D_ + col] = bfs(acc[br][dblk][r] * invq);
            }
        }
    }
}

// ---------- launch ----------
extern "C" void kernel_launch(void* const* d_in, const int* in_sizes, int n_in,
                              void* d_out, int out_size, void* d_ws, size_t ws_size,
                              hipStream_t stream) {
    const float* tokens = (const float*)d_in[0];
    const float* Wq = (const float*)d_in[1];
    const float* bq = (const float*)d_in[2];
    const float* Wk = (const float*)d_in[3];
    const float* bk = (const float*)d_in[4];
    const float* Wv = (const float*)d_in[5];
    const float* bv = (const float*)d_in[6];
    const float* Wo = (const float*)d_in[7];
    const float* bo = (const float*)d_in[8];

    const size_t MB = 1048576;
    if (ws_size < 64 * MB) return;  // need 64 MB scratch
    char* ws = (char*)d_ws;
    short* Xbf = (short*)(ws + 0 * MB);    // [4096][1024] bf16
    short* WqT = (short*)(ws + 8 * MB);    // [1024][1024] bf16 (transposed)
    short* WkT = (short*)(ws + 10 * MB);
    short* WvT = (short*)(ws + 12 * MB);
    short* WoT = (short*)(ws + 14 * MB);
    short* Qb  = (short*)(ws + 16 * MB);   // [4096][1024], pre-scaled by CP_
    short* Kbf = (short*)(ws + 24 * MB);
    short* Vb  = (short*)(ws + 32 * MB);
    short* Vt  = (short*)(ws + 40 * MB);   // [2][16][64][2048]
    short* featNeg = (short*)(ws + 48 * MB);  // [4096][1024]
    short* featPos = (short*)(ws + 56 * MB);  // contiguous after featNeg

    cast_f32_bf16_kernel<<<2048, 256, 0, stream>>>(tokens, Xbf, BS_ * D_ / 8);

    dim3 tg(16, 16);
    transpose_cast_f32_kernel<<<tg, 256, 0, stream>>>(Wq, WqT, D_, D_);
    transpose_cast_f32_kernel<<<tg, 256, 0, stream>>>(Wk, WkT, D_, D_);
    transpose_cast_f32_kernel<<<tg, 256, 0, stream>>>(Wv, WvT, D_, D_);
    transpose_cast_f32_kernel<<<tg, 256, 0, stream>>>(Wo, WoT, D_, D_);

    dim3 gq(D_ / 128, BS_ / 128);  // (8, 32)
    gemm_bt_kernel<0><<<gq, 256, 0, stream>>>(Xbf, WqT, bq, Qb, BS_, D_, D_, CP_);
    gemm_bt_kernel<0><<<gq, 256, 0, stream>>>(Xbf, WkT, bk, Kbf, BS_, D_, D_, 1.0f);
    gemm_bt_kernel<0><<<gq, 256, 0, stream>>>(Xbf, WvT, bv, Vb, BS_, D_, D_, 1.0f);

    transpose_v_kernel<<<dim3(S_ / 64, H_, B_), 256, 0, stream>>>(Vb, Vt);

    attn_kernel<<<dim3(S_ / 128, H_, B_), 256, 0, stream>>>(Qb, Kbf, Vt, featNeg, featPos);

    // final projection on both branches at once: [8192][1024] -> d_out f32
    gemm_bt_kernel<1><<<dim3(D_ / 128, 2 * BS_ / 128), 256, 0, stream>>>(
        featNeg, WoT, bo, d_out, 2 * BS_, D_, D_, 1.0f);
}

// Round 7
// 230.323 us; speedup vs baseline: 1.6905x; 1.6905x over previous
//
#include <hip/hip_runtime.h>
#include <hip/hip_bf16.h>

using bf16x8 = __attribute__((ext_vector_type(8))) short;
using f32x4  = __attribute__((ext_vector_type(4))) float;
using f32x16 = __attribute__((ext_vector_type(16))) float;
using u32x4  = __attribute__((ext_vector_type(4))) unsigned;

static constexpr int B_ = 2, S_ = 2048, D_ = 1024, H_ = 16, HD_ = 64;
static constexpr int BS_ = B_ * S_;                  // 4096 rows
static constexpr float CP_ = 0.18033688011112042f;   // log2(e)/sqrt(64)

// ---------- helpers ----------
__device__ __forceinline__ unsigned short bfbits(float x) {
    unsigned u = __builtin_bit_cast(unsigned, x);
    unsigned r = (u + 0x7fffu + ((u >> 16) & 1u)) >> 16;   // RNE
    return (unsigned short)r;
}
__device__ __forceinline__ short bfs(float x) { return (short)bfbits(x); }

__device__ __forceinline__ unsigned cvt_pk_bf16(float lo, float hi) {
    unsigned r;
    asm("v_cvt_pk_bf16_f32 %0, %1, %2" : "=v"(r) : "v"(lo), "v"(hi));
    return r;
}
__device__ __forceinline__ void gload_lds16(const short* g, short* l) {
    __builtin_amdgcn_global_load_lds(
        (const __attribute__((address_space(1))) void*)g,
        (__attribute__((address_space(3))) void*)l, 16, 0, 0);
}

// ---------- cast tokens f32 -> bf16 ----------
__global__ void cast_f32_bf16_kernel(const float* __restrict__ in,
                                     short* __restrict__ out, int n8) {
    int i = blockIdx.x * blockDim.x + threadIdx.x;
    if (i >= n8) return;
    const float4* p = (const float4*)in + (size_t)i * 2;
    float4 a = p[0], b = p[1];
    short tmp[8] = { bfs(a.x), bfs(a.y), bfs(a.z), bfs(a.w),
                     bfs(b.x), bfs(b.y), bfs(b.z), bfs(b.w) };
    *(int4*)(out + (size_t)i * 8) = *(int4*)tmp;
}

// ---------- transpose+cast all 4 weights: [1024][1024] f32 -> bf16 transposed ----------
// WT holds [WqT | WkT | WvT | WoT] contiguously, each [1024][1024].
__global__ void transpose_cast4_kernel(const float* __restrict__ Wq,
                                       const float* __restrict__ Wk,
                                       const float* __restrict__ Wv,
                                       const float* __restrict__ Wo,
                                       short* __restrict__ WT) {
    __shared__ short tile[64][65];
    const float* srcs[4] = {Wq, Wk, Wv, Wo};
    const float* in = srcs[blockIdx.z];
    short* out = WT + (size_t)blockIdx.z * D_ * D_;
    int t = threadIdx.x;
    int r0 = blockIdx.y * 64, c0 = blockIdx.x * 64;
    int lr = t >> 2, lc0 = (t & 3) * 16;
    const float4* src = (const float4*)(in + (size_t)(r0 + lr) * D_ + c0 + lc0);
#pragma unroll
    for (int v = 0; v < 4; v++) {
        float4 f = src[v];
        tile[lr][lc0 + v * 4 + 0] = bfs(f.x);
        tile[lr][lc0 + v * 4 + 1] = bfs(f.y);
        tile[lr][lc0 + v * 4 + 2] = bfs(f.z);
        tile[lr][lc0 + v * 4 + 3] = bfs(f.w);
    }
    __syncthreads();
    int oc = t >> 2, os0 = (t & 3) * 16;
    short tmp[16];
#pragma unroll
    for (int j = 0; j < 16; j++) tmp[j] = tile[os0 + j][oc];
    short* dst = out + (size_t)(c0 + oc) * D_ + r0 + os0;
    *(int4*)(dst) = *(int4*)(tmp);
    *(int4*)(dst + 8) = *(int4*)(tmp + 8);
}

// ---------- bf16 GEMM: C[M][N] = A[M][K] * BT[N][K]^T + bias ----------
// MODE 0: QKV fused — bf16 out, tri-bias (bq|bk|bv by col/1024), *CP_ on Q cols.
// MODE 1: final   — f32 out, single bias.
template <int MODE>
__global__ __launch_bounds__(256, 2)
void gemm_bt_kernel(const short* __restrict__ A, const short* __restrict__ BT,
                    const float* __restrict__ bp0, const float* __restrict__ bp1,
                    const float* __restrict__ bp2, void* __restrict__ Cout,
                    int M, int N, int K) {
    __shared__ __align__(16) short As[128 * 32];
    __shared__ __align__(16) short Bs[128 * 32];
    int t = threadIdx.x;
    int w = t >> 6, l = t & 63;
    int lq = l & 15, g = l >> 4;
    int rowBase = blockIdx.y * 128, colBase = blockIdx.x * 128;
    int wrow = (w >> 1) * 64, wcol = (w & 1) * 64;
    f32x4 acc[4][4] = {};
    const short* ap0 = A + (size_t)(rowBase + (t >> 2)) * K + (t & 3) * 8;
    const short* ap1 = ap0 + (size_t)64 * K;
    const short* bpA = BT + (size_t)(colBase + (t >> 2)) * K + (t & 3) * 8;
    const short* bpB = bpA + (size_t)64 * K;
    for (int kt = 0; kt < K; kt += 32) {
        __syncthreads();
        gload_lds16(ap0 + kt, &As[t * 8]);
        gload_lds16(ap1 + kt, &As[t * 8 + 2048]);
        gload_lds16(bpA + kt, &Bs[t * 8]);
        gload_lds16(bpB + kt, &Bs[t * 8 + 2048]);
        __syncthreads();
        bf16x8 af[4], bfr[4];
#pragma unroll
        for (int mi = 0; mi < 4; mi++)
            af[mi] = *(const bf16x8*)(&As[(wrow + mi * 16 + lq) * 32 + 8 * g]);
#pragma unroll
        for (int ni = 0; ni < 4; ni++)
            bfr[ni] = *(const bf16x8*)(&Bs[(wcol + ni * 16 + lq) * 32 + 8 * g]);
#pragma unroll
        for (int mi = 0; mi < 4; mi++)
#pragma unroll
            for (int ni = 0; ni < 4; ni++)
                acc[mi][ni] = __builtin_amdgcn_mfma_f32_16x16x32_bf16(
                    af[mi], bfr[ni], acc[mi][ni], 0, 0, 0);
    }
#pragma unroll
    for (int mi = 0; mi < 4; mi++)
#pragma unroll
        for (int ni = 0; ni < 4; ni++) {
            int col = colBase + wcol + ni * 16 + lq;
            float bias, scale = 1.0f;
            if (MODE == 0) {
                const float* bp = (col < 1024) ? bp0 : ((col < 2048) ? bp1 : bp2);
                bias = bp[col & 1023];
                if (col < 1024) scale = CP_;
            } else {
                bias = bp0[col];
            }
#pragma unroll
            for (int r = 0; r < 4; r++) {
                int row = rowBase + wrow + mi * 16 + 4 * g + r;
                float v = (acc[mi][ni][r] + bias) * scale;
                if (MODE == 1)
                    ((float*)Cout)[(size_t)row * N + col] = v;
                else
                    ((short*)Cout)[(size_t)row * N + col] = bfs(v);
            }
        }
}

// ---------- pack Q,K into MFMA-fragment-major layout ----------
// Qf/Kf per (b,h): [64 tiles][4 hf][64 lanes][8] bf16 (131072 elems = 256KB).
// Element: X[b][tile*32 + (l&31)][h][16*hf + 8*(l>>5) + j]  (X = Q or K cols of QKV)
__global__ void pack_qk_kernel(const short* __restrict__ QKV,
                               short* __restrict__ Qf, short* __restrict__ Kf) {
    int t = threadIdx.x;
    int l = t & 63, hf = t >> 6;         // 256 threads = 4 hf x 64 lanes
    int tile = blockIdx.x;               // 0..63
    int h = blockIdx.y;                  // 0..15
    int z = blockIdx.z; int b = z & 1, src = z >> 1;   // src 0=Q, 1=K
    int s = tile * 32 + (l & 31);
    int d = 16 * hf + 8 * (l >> 5);
    const short* sp = QKV + (size_t)(b * S_ + s) * 3072 + src * 1024 + h * 64 + d;
    short* dst = (src ? Kf : Qf) +
                 ((((size_t)(b * H_ + h) * 64 + tile) * 4 + hf) * 64 + l) * 8;
    *(int4*)dst = *(const int4*)sp;
}

// ---------- pack V into PV B-fragment layout (permuted key order) ----------
// Vf per (b,h): [64 tiles][2 dblk][2 hf][64 lanes][8] bf16 (131072 elems).
// Element: V[b][tile*32 + 16*hf + (j&3) + 8*(j>>2) + 4*(l>>5)][h][dblk*32 + (l&31)]
__global__ void pack_v_kernel(const short* __restrict__ QKV,
                              short* __restrict__ Vf) {
    __shared__ short Vl[256][68];   // +4 pad to cut write bank conflicts
    int t = threadIdx.x;
    int sgrp = blockIdx.x, h = blockIdx.y, b = blockIdx.z;
    const short* sp = QKV + (size_t)(b * S_ + sgrp * 256 + t) * 3072 + 2048 + h * 64;
#pragma unroll
    for (int c = 0; c < 8; c++)
        *(int4*)(&Vl[t][c * 8]) = *(const int4*)(sp + c * 8);
    __syncthreads();
    int l = t & 63, hf = (t >> 6) & 1, dblk = t >> 7;
    int h2 = l >> 5, d = dblk * 32 + (l & 31);
    short* dstbase = Vf + (size_t)(b * H_ + h) * 131072;
#pragma unroll
    for (int k = 0; k < 8; k++) {
        short tmp[8];
#pragma unroll
        for (int j = 0; j < 8; j++) {
            int sl = k * 32 + 16 * hf + (j & 3) + 8 * (j >> 2) + 4 * h2;
            tmp[j] = Vl[sl][d];
        }
        int tile = sgrp * 8 + k;
        short* dst = dstbase + ((((size_t)tile * 2 + dblk) * 2 + hf) * 64 + l) * 8;
        *(int4*)dst = *(int4*)tmp;
    }
}

// ---------- fused two-branch attention, 32x32 MFMA, in-register softmax ----------
// Wave = 32 q-rows of one head. Swapped QK^T (mfma32(K,Q)) => st[r] =
// S[key=(r&3)+8*(r>>2)+4*h2][q=l&31]. Q pre-scaled by log2(e)/sqrt(64), so
// p = exp2(+/-st). cvt_pk fragments feed PV directly with key-PERMUTED V
// fragments (Vf pre-packed in that order); MFMA's key-sum is order-invariant.
// All inner-loop loads are contiguous 16B/lane (fragment-major buffers).
__global__ __launch_bounds__(256, 2)
void attn_kernel(const short* __restrict__ Qf, const short* __restrict__ Kf,
                 const short* __restrict__ Vf, short* __restrict__ featNeg,
                 short* __restrict__ featPos) {
    int t = threadIdx.x;
    int w = t >> 6, l = t & 63;
    int l31 = l & 31, h2 = l >> 5;
    int qtile = blockIdx.x;   // 0..15
    int hh = blockIdx.y, b = blockIdx.z;
    int qb0 = qtile * 128 + w * 32;
    size_t hb = (size_t)(b * H_ + hh) * 131072;

    // Q fragments for this wave's 32 q-rows
    bf16x8 qa[4];
    const short* qp = Qf + hb + ((size_t)(qb0 >> 5) * 4 * 64 + l) * 8;
#pragma unroll
    for (int hf = 0; hf < 4; hf++)
        qa[hf] = *(const bf16x8*)(qp + hf * 512);

    f32x16 acc[2][2] = {};   // [branch][dblk]
    float lsum[2] = {0.f, 0.f};

    const short* kp0 = Kf + hb + l * 8;
    const short* vp0 = Vf + hb + l * 8;

    for (int tile = 0; tile < 64; tile++) {
        const short* kp = kp0 + (size_t)tile * 2048;
        const short* vp = vp0 + (size_t)tile * 2048;
        bf16x8 ka[4];
#pragma unroll
        for (int hf = 0; hf < 4; hf++)
            ka[hf] = *(const bf16x8*)(kp + hf * 512);
        bf16x8 vb[2][2];
#pragma unroll
        for (int dblk = 0; dblk < 2; dblk++)
#pragma unroll
            for (int hf = 0; hf < 2; hf++)
                vb[dblk][hf] = *(const bf16x8*)(vp + (dblk * 2 + hf) * 512);

        f32x16 st = {};
#pragma unroll
        for (int hf = 0; hf < 4; hf++)
            st = __builtin_amdgcn_mfma_f32_32x32x16_bf16(ka[hf], qa[hf], st, 0, 0, 0);

#pragma unroll
        for (int br = 0; br < 2; br++) {
            unsigned c[8];
            float s0 = 0.f, s1 = 0.f;
#pragma unroll
            for (int i = 0; i < 8; i++) {
                float plo = __builtin_amdgcn_exp2f(br ? st[2 * i] : -st[2 * i]);
                float phi = __builtin_amdgcn_exp2f(br ? st[2 * i + 1] : -st[2 * i + 1]);
                if (i & 1) s1 += plo + phi; else s0 += plo + phi;
                c[i] = cvt_pk_bf16(plo, phi);
            }
            lsum[br] += s0 + s1;
            u32x4 lo4 = {c[0], c[1], c[2], c[3]};
            u32x4 hi4 = {c[4], c[5], c[6], c[7]};
            bf16x8 pa0 = __builtin_bit_cast(bf16x8, lo4);   // key-slots, keys 0..15
            bf16x8 pa1 = __builtin_bit_cast(bf16x8, hi4);   // key-slots, keys 16..31
#pragma unroll
            for (int dblk = 0; dblk < 2; dblk++) {
                acc[br][dblk] = __builtin_amdgcn_mfma_f32_32x32x16_bf16(
                    pa0, vb[dblk][0], acc[br][dblk], 0, 0, 0);
                acc[br][dblk] = __builtin_amdgcn_mfma_f32_32x32x16_bf16(
                    pa1, vb[dblk][1], acc[br][dblk], 0, 0, 0);
            }
        }
    }

#pragma unroll
    for (int br = 0; br < 2; br++) {
        float ls = lsum[br];
        ls += __shfl_xor(ls, 32);
        float inv = 1.0f / ls;
        short* dst = br ? featPos : featNeg;
#pragma unroll
        for (int r = 0; r < 16; r++) {
            int qr = (r & 3) + 8 * (r >> 2) + 4 * h2;
            float invq = __shfl(inv, qr);   // inv lives at lanes l31==q
            size_t row = (size_t)(b * S_ + qb0 + qr);
#pragma unroll
            for (int dblk = 0; dblk < 2; dblk++) {
                int col = hh * HD_ + dblk * 32 + l31;
                dst[row * D_ + col] = bfs(acc[br][dblk][r] * invq);
            }
        }
    }
}

// ---------- launch ----------
extern "C" void kernel_launch(void* const* d_in, const int* in_sizes, int n_in,
                              void* d_out, int out_size, void* d_ws, size_t ws_size,
                              hipStream_t stream) {
    const float* tokens = (const float*)d_in[0];
    const float* Wq = (const float*)d_in[1];
    const float* bq = (const float*)d_in[2];
    const float* Wk = (const float*)d_in[3];
    const float* bk = (const float*)d_in[4];
    const float* Wv = (const float*)d_in[5];
    const float* bv = (const float*)d_in[6];
    const float* Wo = (const float*)d_in[7];
    const float* bo = (const float*)d_in[8];

    const size_t MB = 1048576;
    if (ws_size < 64 * MB) return;  // need 64 MB scratch
    char* ws = (char*)d_ws;
    short* Xbf = (short*)(ws + 0 * MB);      // [4096][1024] bf16, 8MB
    short* WT  = (short*)(ws + 8 * MB);      // [WqT|WkT|WvT|WoT], 8MB
    short* QKV = (short*)(ws + 16 * MB);     // [4096][3072] bf16, 24MB (dead after packs)
    short* featNeg = (short*)(ws + 16 * MB); // [4096][1024], aliases QKV (safe)
    short* featPos = (short*)(ws + 24 * MB);
    short* Qf = (short*)(ws + 40 * MB);      // fragment-packed, 8MB each
    short* Kf = (short*)(ws + 48 * MB);
    short* Vf = (short*)(ws + 56 * MB);

    cast_f32_bf16_kernel<<<2048, 256, 0, stream>>>(tokens, Xbf, BS_ * D_ / 8);

    transpose_cast4_kernel<<<dim3(16, 16, 4), 256, 0, stream>>>(Wq, Wk, Wv, Wo, WT);

    // fused QKV projection: [4096][3072]
    gemm_bt_kernel<0><<<dim3(3072 / 128, BS_ / 128), 256, 0, stream>>>(
        Xbf, WT, bq, bk, bv, QKV, BS_, 3072, D_);

    pack_qk_kernel<<<dim3(64, 16, 4), 256, 0, stream>>>(QKV, Qf, Kf);
    pack_v_kernel<<<dim3(8, 16, 2), 256, 0, stream>>>(QKV, Vf);

    attn_kernel<<<dim3(S_ / 128, H_, B_), 256, 0, stream>>>(Qf, Kf, Vf, featNeg, featPos);

    // final projection on both branches at once: [8192][1024] -> d_out f32
    gemm_bt_kernel<1><<<dim3(D_ / 128, 2 * BS_ / 128), 256, 0, stream>>>(
        featNeg, WT + (size_t)3 * D_ * D_, bo, nullptr, nullptr, d_out,
        2 * BS_, D_, D_);
}

// Round 8
// 228.381 us; speedup vs baseline: 1.7049x; 1.0085x over previous
//
#include <hip/hip_runtime.h>
#include <hip/hip_bf16.h>

using bf16x8 = __attribute__((ext_vector_type(8))) short;
using f32x4  = __attribute__((ext_vector_type(4))) float;
using f32x16 = __attribute__((ext_vector_type(16))) float;
using u32x4  = __attribute__((ext_vector_type(4))) unsigned;

static constexpr int B_ = 2, S_ = 2048, D_ = 1024, H_ = 16, HD_ = 64;
static constexpr int BS_ = B_ * S_;                  // 4096 rows
static constexpr float CP_ = 0.18033688011112042f;   // log2(e)/sqrt(64)

// ---------- helpers ----------
__device__ __forceinline__ unsigned short bfbits(float x) {
    unsigned u = __builtin_bit_cast(unsigned, x);
    unsigned r = (u + 0x7fffu + ((u >> 16) & 1u)) >> 16;   // RNE
    return (unsigned short)r;
}
__device__ __forceinline__ short bfs(float x) { return (short)bfbits(x); }

__device__ __forceinline__ unsigned cvt_pk_bf16(float lo, float hi) {
    unsigned r;
    asm("v_cvt_pk_bf16_f32 %0, %1, %2" : "=v"(r) : "v"(lo), "v"(hi));
    return r;
}
__device__ __forceinline__ void gload_lds16(const short* g, short* l) {
    __builtin_amdgcn_global_load_lds(
        (const __attribute__((address_space(1))) void*)g,
        (__attribute__((address_space(3))) void*)l, 16, 0, 0);
}

// ---------- cast tokens f32 -> bf16 ----------
__global__ void cast_f32_bf16_kernel(const float* __restrict__ in,
                                     short* __restrict__ out, int n8) {
    int i = blockIdx.x * blockDim.x + threadIdx.x;
    if (i >= n8) return;
    const float4* p = (const float4*)in + (size_t)i * 2;
    float4 a = p[0], b = p[1];
    short tmp[8] = { bfs(a.x), bfs(a.y), bfs(a.z), bfs(a.w),
                     bfs(b.x), bfs(b.y), bfs(b.z), bfs(b.w) };
    *(int4*)(out + (size_t)i * 8) = *(int4*)tmp;
}

// ---------- transpose+cast all 4 weights: [1024][1024] f32 -> bf16 transposed ----------
__global__ void transpose_cast4_kernel(const float* __restrict__ Wq,
                                       const float* __restrict__ Wk,
                                       const float* __restrict__ Wv,
                                       const float* __restrict__ Wo,
                                       short* __restrict__ WT) {
    __shared__ short tile[64][65];
    const float* srcs[4] = {Wq, Wk, Wv, Wo};
    const float* in = srcs[blockIdx.z];
    short* out = WT + (size_t)blockIdx.z * D_ * D_;
    int t = threadIdx.x;
    int r0 = blockIdx.y * 64, c0 = blockIdx.x * 64;
    int lr = t >> 2, lc0 = (t & 3) * 16;
    const float4* src = (const float4*)(in + (size_t)(r0 + lr) * D_ + c0 + lc0);
#pragma unroll
    for (int v = 0; v < 4; v++) {
        float4 f = src[v];
        tile[lr][lc0 + v * 4 + 0] = bfs(f.x);
        tile[lr][lc0 + v * 4 + 1] = bfs(f.y);
        tile[lr][lc0 + v * 4 + 2] = bfs(f.z);
        tile[lr][lc0 + v * 4 + 3] = bfs(f.w);
    }
    __syncthreads();
    int oc = t >> 2, os0 = (t & 3) * 16;
    short tmp[16];
#pragma unroll
    for (int j = 0; j < 16; j++) tmp[j] = tile[os0 + j][oc];
    short* dst = out + (size_t)(c0 + oc) * D_ + r0 + os0;
    *(int4*)(dst) = *(int4*)(tmp);
    *(int4*)(dst + 8) = *(int4*)(tmp + 8);
}

// ---------- bf16 GEMM: C[M][N] = A[M][K] * BT[N][K]^T + bias ----------
// 1D grid with XCD-aware swizzle (nwg % 8 == 0 in all uses).
// MODE 0: QKV fused — bf16 out, tri-bias (bq|bk|bv by col/1024), *CP_ on Q cols.
// MODE 1: final   — f32 out, single bias.
template <int MODE>
__global__ __launch_bounds__(256, 2)
void gemm_bt_kernel(const short* __restrict__ A, const short* __restrict__ BT,
                    const float* __restrict__ bp0, const float* __restrict__ bp1,
                    const float* __restrict__ bp2, void* __restrict__ Cout,
                    int M, int N, int K, int nBx, int cpx) {
    __shared__ __align__(16) short As[128 * 32];
    __shared__ __align__(16) short Bs[128 * 32];
    int bid = blockIdx.x;
    int wg = (bid & 7) * cpx + (bid >> 3);   // XCD swizzle (bijective: nwg%8==0)
    int bx = wg % nBx, by = wg / nBx;
    int t = threadIdx.x;
    int w = t >> 6, l = t & 63;
    int lq = l & 15, g = l >> 4;
    int rowBase = by * 128, colBase = bx * 128;
    int wrow = (w >> 1) * 64, wcol = (w & 1) * 64;
    f32x4 acc[4][4] = {};
    const short* ap0 = A + (size_t)(rowBase + (t >> 2)) * K + (t & 3) * 8;
    const short* ap1 = ap0 + (size_t)64 * K;
    const short* bpA = BT + (size_t)(colBase + (t >> 2)) * K + (t & 3) * 8;
    const short* bpB = bpA + (size_t)64 * K;
    for (int kt = 0; kt < K; kt += 32) {
        __syncthreads();
        gload_lds16(ap0 + kt, &As[t * 8]);
        gload_lds16(ap1 + kt, &As[t * 8 + 2048]);
        gload_lds16(bpA + kt, &Bs[t * 8]);
        gload_lds16(bpB + kt, &Bs[t * 8 + 2048]);
        __syncthreads();
        bf16x8 af[4], bfr[4];
#pragma unroll
        for (int mi = 0; mi < 4; mi++)
            af[mi] = *(const bf16x8*)(&As[(wrow + mi * 16 + lq) * 32 + 8 * g]);
#pragma unroll
        for (int ni = 0; ni < 4; ni++)
            bfr[ni] = *(const bf16x8*)(&Bs[(wcol + ni * 16 + lq) * 32 + 8 * g]);
#pragma unroll
        for (int mi = 0; mi < 4; mi++)
#pragma unroll
            for (int ni = 0; ni < 4; ni++)
                acc[mi][ni] = __builtin_amdgcn_mfma_f32_16x16x32_bf16(
                    af[mi], bfr[ni], acc[mi][ni], 0, 0, 0);
    }
#pragma unroll
    for (int mi = 0; mi < 4; mi++)
#pragma unroll
        for (int ni = 0; ni < 4; ni++) {
            int col = colBase + wcol + ni * 16 + lq;
            float bias, scale = 1.0f;
            if (MODE == 0) {
                const float* bp = (col < 1024) ? bp0 : ((col < 2048) ? bp1 : bp2);
                bias = bp[col & 1023];
                if (col < 1024) scale = CP_;
            } else {
                bias = bp0[col];
            }
#pragma unroll
            for (int r = 0; r < 4; r++) {
                int row = rowBase + wrow + mi * 16 + 4 * g + r;
                float v = (acc[mi][ni][r] + bias) * scale;
                if (MODE == 1)
                    ((float*)Cout)[(size_t)row * N + col] = v;
                else
                    ((short*)Cout)[(size_t)row * N + col] = bfs(v);
            }
        }
}

// ---------- pack Q,K into MFMA-fragment-major layout ----------
__global__ void pack_qk_kernel(const short* __restrict__ QKV,
                               short* __restrict__ Qf, short* __restrict__ Kf) {
    int t = threadIdx.x;
    int l = t & 63, hf = t >> 6;         // 256 threads = 4 hf x 64 lanes
    int tile = blockIdx.x;               // 0..63
    int h = blockIdx.y;                  // 0..15
    int z = blockIdx.z; int b = z & 1, src = z >> 1;   // src 0=Q, 1=K
    int s = tile * 32 + (l & 31);
    int d = 16 * hf + 8 * (l >> 5);
    const short* sp = QKV + (size_t)(b * S_ + s) * 3072 + src * 1024 + h * 64 + d;
    short* dst = (src ? Kf : Qf) +
                 ((((size_t)(b * H_ + h) * 64 + tile) * 4 + hf) * 64 + l) * 8;
    *(int4*)dst = *(const int4*)sp;
}

// ---------- pack V into PV B-fragment layout (permuted key order) ----------
__global__ void pack_v_kernel(const short* __restrict__ QKV,
                              short* __restrict__ Vf) {
    __shared__ short Vl[256][68];   // +4 pad to cut write bank conflicts
    int t = threadIdx.x;
    int sgrp = blockIdx.x, h = blockIdx.y, b = blockIdx.z;
    const short* sp = QKV + (size_t)(b * S_ + sgrp * 256 + t) * 3072 + 2048 + h * 64;
#pragma unroll
    for (int c = 0; c < 8; c++)
        *(int4*)(&Vl[t][c * 8]) = *(const int4*)(sp + c * 8);
    __syncthreads();
    int l = t & 63, hf = (t >> 6) & 1, dblk = t >> 7;
    int h2 = l >> 5, d = dblk * 32 + (l & 31);
    short* dstbase = Vf + (size_t)(b * H_ + h) * 131072;
#pragma unroll
    for (int k = 0; k < 8; k++) {
        short tmp[8];
#pragma unroll
        for (int j = 0; j < 8; j++) {
            int sl = k * 32 + 16 * hf + (j & 3) + 8 * (j >> 2) + 4 * h2;
            tmp[j] = Vl[sl][d];
        }
        int tile = sgrp * 8 + k;
        short* dst = dstbase + ((((size_t)tile * 2 + dblk) * 2 + hf) * 64 + l) * 8;
        *(int4*)dst = *(int4*)tmp;
    }
}

// ---------- fused two-branch attention, 32x32 MFMA, in-register softmax ----------
// Wave = 32 q-rows of one head. Swapped QK^T (mfma32(K,Q)); Q pre-scaled by
// log2(e)/sqrt(64) so p = exp2(+/-st). cvt_pk fragments feed PV directly with
// key-PERMUTED pre-packed V fragments. Row-sum (softmax denominator) is
// computed by MFMA against an all-ones B-fragment: acc_l rows == acc rows, so
// the epilogue needs no cross-lane shfl at all.
// XCD swizzle: 16 q-tile blocks of one (b,h) share 512KB K/V — group on XCD.
__global__ __launch_bounds__(256, 2)
void attn_kernel(const short* __restrict__ Qf, const short* __restrict__ Kf,
                 const short* __restrict__ Vf, short* __restrict__ featNeg,
                 short* __restrict__ featPos) {
    int bid = blockIdx.x;                       // 512 blocks, 1D
    int wg = (bid & 7) * 64 + (bid >> 3);       // XCD swizzle (512 % 8 == 0)
    int qtile = wg & 15, hh = (wg >> 4) & 15, b = wg >> 8;
    int t = threadIdx.x;
    int w = t >> 6, l = t & 63;
    int l31 = l & 31, h2 = l >> 5;
    int qb0 = qtile * 128 + w * 32;
    size_t hb = (size_t)(b * H_ + hh) * 131072;

    // Q fragments for this wave's 32 q-rows
    bf16x8 qa[4];
    const short* qp = Qf + hb + ((size_t)(qb0 >> 5) * 4 * 64 + l) * 8;
#pragma unroll
    for (int hf = 0; hf < 4; hf++)
        qa[hf] = *(const bf16x8*)(qp + hf * 512);

    // all-ones bf16 B-fragment for the row-sum MFMA
    bf16x8 ones;
#pragma unroll
    for (int j = 0; j < 8; j++) ones[j] = (short)0x3F80;

    f32x16 acc[2][2] = {};   // [branch][dblk]
    f32x16 acc_l[2] = {};    // [branch] row-sums (all cols equal)

    const short* kp0 = Kf + hb + l * 8;
    const short* vp0 = Vf + hb + l * 8;

#pragma unroll 2
    for (int tile = 0; tile < 64; tile++) {
        const short* kp = kp0 + (size_t)tile * 2048;
        const short* vp = vp0 + (size_t)tile * 2048;
        bf16x8 ka[4];
#pragma unroll
        for (int hf = 0; hf < 4; hf++)
            ka[hf] = *(const bf16x8*)(kp + hf * 512);
        bf16x8 vb[2][2];
#pragma unroll
        for (int dblk = 0; dblk < 2; dblk++)
#pragma unroll
            for (int hf = 0; hf < 2; hf++)
                vb[dblk][hf] = *(const bf16x8*)(vp + (dblk * 2 + hf) * 512);

        f32x16 st = {};
        __builtin_amdgcn_s_setprio(1);
#pragma unroll
        for (int hf = 0; hf < 4; hf++)
            st = __builtin_amdgcn_mfma_f32_32x32x16_bf16(ka[hf], qa[hf], st, 0, 0, 0);
        __builtin_amdgcn_s_setprio(0);

#pragma unroll
        for (int br = 0; br < 2; br++) {
            unsigned c[8];
#pragma unroll
            for (int i = 0; i < 8; i++) {
                float plo = __builtin_amdgcn_exp2f(br ? st[2 * i] : -st[2 * i]);
                float phi = __builtin_amdgcn_exp2f(br ? st[2 * i + 1] : -st[2 * i + 1]);
                c[i] = cvt_pk_bf16(plo, phi);
            }
            u32x4 lo4 = {c[0], c[1], c[2], c[3]};
            u32x4 hi4 = {c[4], c[5], c[6], c[7]};
            bf16x8 pa0 = __builtin_bit_cast(bf16x8, lo4);   // key-slots, keys 0..15
            bf16x8 pa1 = __builtin_bit_cast(bf16x8, hi4);   // key-slots, keys 16..31
            __builtin_amdgcn_s_setprio(1);
#pragma unroll
            for (int dblk = 0; dblk < 2; dblk++) {
                acc[br][dblk] = __builtin_amdgcn_mfma_f32_32x32x16_bf16(
                    pa0, vb[dblk][0], acc[br][dblk], 0, 0, 0);
                acc[br][dblk] = __builtin_amdgcn_mfma_f32_32x32x16_bf16(
                    pa1, vb[dblk][1], acc[br][dblk], 0, 0, 0);
            }
            acc_l[br] = __builtin_amdgcn_mfma_f32_32x32x16_bf16(pa0, ones, acc_l[br], 0, 0, 0);
            acc_l[br] = __builtin_amdgcn_mfma_f32_32x32x16_bf16(pa1, ones, acc_l[br], 0, 0, 0);
            __builtin_amdgcn_s_setprio(0);
        }
    }

#pragma unroll
    for (int br = 0; br < 2; br++) {
        short* dst = br ? featPos : featNeg;
#pragma unroll
        for (int r = 0; r < 16; r++) {
            int qr = (r & 3) + 8 * (r >> 2) + 4 * h2;
            float invq = 1.0f / acc_l[br][r];   // row-sum lives at matching r
            size_t row = (size_t)(b * S_ + qb0 + qr);
#pragma unroll
            for (int dblk = 0; dblk < 2; dblk++) {
                int col = hh * HD_ + dblk * 32 + l31;
                dst[row * D_ + col] = bfs(acc[br][dblk][r] * invq);
            }
        }
    }
}

// ---------- launch ----------
extern "C" void kernel_launch(void* const* d_in, const int* in_sizes, int n_in,
                              void* d_out, int out_size, void* d_ws, size_t ws_size,
                              hipStream_t stream) {
    const float* tokens = (const float*)d_in[0];
    const float* Wq = (const float*)d_in[1];
    const float* bq = (const float*)d_in[2];
    const float* Wk = (const float*)d_in[3];
    const float* bk = (const float*)d_in[4];
    const float* Wv = (const float*)d_in[5];
    const float* bv = (const float*)d_in[6];
    const float* Wo = (const float*)d_in[7];
    const float* bo = (const float*)d_in[8];

    const size_t MB = 1048576;
    if (ws_size < 64 * MB) return;  // need 64 MB scratch
    char* ws = (char*)d_ws;
    short* Xbf = (short*)(ws + 0 * MB);      // [4096][1024] bf16, 8MB
    short* WT  = (short*)(ws + 8 * MB);      // [WqT|WkT|WvT|WoT], 8MB
    short* QKV = (short*)(ws + 16 * MB);     // [4096][3072] bf16, 24MB (dead after packs)
    short* featNeg = (short*)(ws + 16 * MB); // [4096][1024], aliases QKV (safe)
    short* featPos = (short*)(ws + 24 * MB);
    short* Qf = (short*)(ws + 40 * MB);      // fragment-packed, 8MB each
    short* Kf = (short*)(ws + 48 * MB);
    short* Vf = (short*)(ws + 56 * MB);

    cast_f32_bf16_kernel<<<2048, 256, 0, stream>>>(tokens, Xbf, BS_ * D_ / 8);

    transpose_cast4_kernel<<<dim3(16, 16, 4), 256, 0, stream>>>(Wq, Wk, Wv, Wo, WT);

    // fused QKV projection: [4096][3072], 768 blocks (XCD-swizzled 1D grid)
    gemm_bt_kernel<0><<<768, 256, 0, stream>>>(
        Xbf, WT, bq, bk, bv, QKV, BS_, 3072, D_, 24, 96);

    pack_qk_kernel<<<dim3(64, 16, 4), 256, 0, stream>>>(QKV, Qf, Kf);
    pack_v_kernel<<<dim3(8, 16, 2), 256, 0, stream>>>(QKV, Vf);

    attn_kernel<<<512, 256, 0, stream>>>(Qf, Kf, Vf, featNeg, featPos);

    // final projection on both branches at once: [8192][1024] -> d_out f32
    gemm_bt_kernel<1><<<512, 256, 0, stream>>>(
        featNeg, WT + (size_t)3 * D_ * D_, bo, nullptr, nullptr, d_out,
        2 * BS_, D_, D_, 8, 64);
}